// Round 8
// baseline (1259.381 us; speedup 1.0000x reference)
//
#include <hip/hip_runtime.h>
#include <hip/hip_bf16.h>

// ---------- types ----------
typedef __attribute__((ext_vector_type(8))) unsigned short u16x8;
typedef __attribute__((ext_vector_type(4))) unsigned short u16x4;
typedef __attribute__((ext_vector_type(4))) unsigned int   u32x4;
typedef __attribute__((ext_vector_type(8))) __bf16         bf16x8;
typedef __attribute__((ext_vector_type(4))) float          f32x4;

#define SS 1024
#define BB 8
#define DD 1024
#define HH 16
#define HDD 64
#define FF 4096
#define MM 8192   // S*B rows

// async global->LDS, 16B per lane; LDS dest is wave-uniform base + lane*16
#define GL16(g, l) __builtin_amdgcn_global_load_lds( \
    (__attribute__((address_space(1))) const void*)(g), \
    (__attribute__((address_space(3))) void*)(l), 16, 0, 0)

__device__ __forceinline__ float bf2f(unsigned short u) {
    return __uint_as_float(((unsigned int)u) << 16);
}
__device__ __forceinline__ unsigned short f2bf(float f) {
    unsigned int u = __float_as_uint(f);
    unsigned int r = (u + 0x7fffu + ((u >> 16) & 1u)) >> 16;  // RNE
    return (unsigned short)r;
}
__device__ __forceinline__ float quantv(float w, float som, float qm) {
    if (qm == 0.f) {  // 1-bit: sign(w)*mean|w|
        float sgn = (w > 0.f) ? 1.f : ((w < 0.f) ? -1.f : 0.f);
        return sgn * som;
    }
    if (som == 0.f) return 0.f;
    float q = rintf(w / som);
    q = fminf(fmaxf(q, -qm - 1.f), qm);
    return q * som;
}

// ---------- stats: per-tensor max|w|, sum|w| (deterministic 2-pass) ----------
__global__ __launch_bounds__(256) void k_stats(const float* __restrict__ w_in, const float* __restrict__ w_out,
                                               const float* __restrict__ w1, const float* __restrict__ w2,
                                               float* __restrict__ pmax, float* __restrict__ psum) {
    const int t = blockIdx.y, blk = blockIdx.x, tid = threadIdx.x;
    const float* base; int n;
    if (t < 4)       { base = w_in  + (size_t)t * 3145728;     n = 3145728; }
    else if (t < 8)  { base = w_out + (size_t)(t-4) * 1048576; n = 1048576; }
    else if (t < 12) { base = w1    + (size_t)(t-8) * 4194304; n = 4194304; }
    else             { base = w2    + (size_t)(t-12) * 4194304; n = 4194304; }
    const int n4 = n >> 2;
    float vmax = 0.f, vsum = 0.f;
    for (int i = blk * 256 + tid; i < n4; i += 65536) {
        float4 v = reinterpret_cast<const float4*>(base)[i];
        float a0 = fabsf(v.x), a1 = fabsf(v.y), a2 = fabsf(v.z), a3 = fabsf(v.w);
        vmax = fmaxf(vmax, fmaxf(fmaxf(a0, a1), fmaxf(a2, a3)));
        vsum += (a0 + a1) + (a2 + a3);
    }
#pragma unroll
    for (int m = 1; m < 64; m <<= 1) { vmax = fmaxf(vmax, __shfl_xor(vmax, m, 64)); vsum += __shfl_xor(vsum, m, 64); }
    __shared__ float sm[4], su[4];
    const int wave = tid >> 6, lane = tid & 63;
    if (lane == 0) { sm[wave] = vmax; su[wave] = vsum; }
    __syncthreads();
    if (tid == 0) {
        pmax[t * 256 + blk] = fmaxf(fmaxf(sm[0], sm[1]), fmaxf(sm[2], sm[3]));
        psum[t * 256 + blk] = (su[0] + su[1]) + (su[2] + su[3]);
    }
}

// ---------- params: final reduce + softmax(alpha) ----------
__global__ __launch_bounds__(256) void k_params(const float* __restrict__ pmax, const float* __restrict__ psum,
                                                const float* __restrict__ alpha, float* __restrict__ P) {
    __shared__ float rm[256], rs[256];
    const int tid = threadIdx.x;
    for (int t = 0; t < 16; ++t) {
        rm[tid] = pmax[t * 256 + tid];
        rs[tid] = psum[t * 256 + tid];
        __syncthreads();
        for (int s = 128; s > 0; s >>= 1) {
            if (tid < s) { rm[tid] = fmaxf(rm[tid], rm[tid + s]); rs[tid] += rs[tid + s]; }
            __syncthreads();
        }
        if (tid == 0) {
            const int nbits[4] = {1, 2, 4, 8};
            const int nb = nbits[t & 3];
            float nsize = (t < 4) ? 3145728.f : ((t < 8) ? 1048576.f : 4194304.f);
            if (nb == 1) { P[16 + 2*t] = rs[0] / nsize; P[17 + 2*t] = 0.f; }
            else { float qm = (float)((1 << (nb - 1)) - 1); P[16 + 2*t] = rm[0] / qm; P[17 + 2*t] = qm; }
        }
        __syncthreads();
    }
    if (tid < 3) {
        float a[4], mx = -1e30f;
#pragma unroll
        for (int i = 0; i < 4; ++i) { a[i] = alpha[tid * 4 + i]; mx = fmaxf(mx, a[i]); }
        float e[4], ssum = 0.f;
#pragma unroll
        for (int i = 0; i < 4; ++i) { e[i] = expf(a[i] - mx); ssum += e[i]; }
#pragma unroll
        for (int i = 0; i < 4; ++i) P[tid * 4 + i] = e[i] / ssum;
    }
}

// ---------- quantize per-branch attn in-proj weights -> bf16 ----------
__global__ __launch_bounds__(256) void k_quant(const float* __restrict__ w, unsigned short* __restrict__ out,
                                               const float* __restrict__ P, int per_tensor, int tbase, int ntot) {
    int i = blockIdx.x * 256 + threadIdx.x;
    if (i >= ntot) return;
    int t = tbase + i / per_tensor;
    out[i] = f2bf(quantv(w[i], P[16 + 2*t], P[17 + 2*t]));
}

// ---------- out-proj: quantize + scale by probs[0][i], K-concat layout ----------
__global__ __launch_bounds__(256) void k_qcat(const float* __restrict__ w_out, unsigned short* __restrict__ out,
                                              const float* __restrict__ P) {
    int j = blockIdx.x * 256 + threadIdx.x;
    if (j >= 4194304) return;
    int d = j >> 12, rr = j & 4095, i = rr >> 10, e = rr & 1023;
    int t = 4 + i;
    float v = quantv(w_out[((size_t)i << 20) + d * 1024 + e], P[16 + 2*t], P[17 + 2*t]);
    out[j] = f2bf(P[i] * v);
}

// ---------- mix quantized FFN weights across branches -> bf16 ----------
__global__ __launch_bounds__(256) void k_mix(const float* __restrict__ w, unsigned short* __restrict__ out,
                                             const float* __restrict__ P, int tbase, int prow, int sz) {
    int i = blockIdx.x * 256 + threadIdx.x;
    if (i >= sz) return;
    float acc = 0.f;
#pragma unroll
    for (int br = 0; br < 4; ++br) {
        int t = tbase + br;
        acc += P[prow * 4 + br] * quantv(w[(size_t)br * sz + i], P[16 + 2*t], P[17 + 2*t]);
    }
    out[i] = f2bf(acc);
}
__global__ __launch_bounds__(256) void k_mixb(const float* __restrict__ b, float* __restrict__ out,
                                              const float* __restrict__ P, int prow, int n) {
    int i = blockIdx.x * 256 + threadIdx.x;
    if (i >= n) return;
    float acc = 0.f;
#pragma unroll
    for (int br = 0; br < 4; ++br) acc += P[prow * 4 + br] * b[(size_t)br * n + i];
    out[i] = acc;
}

// ---------- fp32 -> bf16 cast ----------
__global__ __launch_bounds__(256) void k_cast(const float* __restrict__ in, unsigned short* __restrict__ out, int n4) {
    int i = blockIdx.x * 256 + threadIdx.x;
    if (i >= n4) return;
    float4 v = reinterpret_cast<const float4*>(in)[i];
    u16x4 o; o[0] = f2bf(v.x); o[1] = f2bf(v.y); o[2] = f2bf(v.z); o[3] = f2bf(v.w);
    reinterpret_cast<u16x4*>(out)[i] = o;
}

// ---------- GEMM: C[M,N] = act(A[M,K] @ Bw[N,K]^T + bias)  (R5 structure, best-measured) ----------
// 128x128 tile, 4 waves 2x2, GL16 staging (pre-swizzled source, linear dest),
// 2-phase double-buffered. VPOSE: qkv's V-columns (col>=2048) are scattered
// transposed into VT[hh][b][d][s] instead of C (bf16), Q/K columns stored normally.
__device__ __forceinline__ void store_out(float* C, size_t idx, float v) { C[idx] = v; }
__device__ __forceinline__ void store_out(unsigned short* C, size_t idx, float v) { C[idx] = f2bf(v); }

template <typename OutT, bool GELU, bool VPOSE>
__global__ __launch_bounds__(256) void k_gemm_bt(const unsigned short* __restrict__ A,
                                                 const unsigned short* __restrict__ Bw,
                                                 OutT* __restrict__ C,
                                                 const float* __restrict__ bias,
                                                 unsigned short* __restrict__ VT,
                                                 int M, int N, int K, int XM, int XN) {
    const int gx = gridDim.x, gy = gridDim.y;
    const int flat = blockIdx.x + gx * blockIdx.y;
    const int xcd = flat & 7, r = flat >> 3;
    const int nloc = gx / XN, mloc = gy / XM;
    const int cm = xcd / XN, cn = xcd - cm * XN;
    const int by = cm * mloc + r / nloc;
    const int bx = cn * nloc + (r - (r / nloc) * nloc);

    __shared__ unsigned short As[2][128 * 64];
    __shared__ unsigned short Bs[2][128 * 64];
    const int tid = threadIdx.x;
    const int m0 = by * 128, n0 = bx * 128;
    const int lane = tid & 63, wave = tid >> 6;
    const int wr = wave >> 1, wc = wave & 1;
    const int lr = lane & 15, lg = lane >> 4;
    const int rsub = lane >> 3;                 // row within 8-row group
    const int csub = ((lane & 7) ^ rsub) * 8;   // pre-swizzled k-chunk (shorts)
    const size_t aoff = (size_t)(m0 + rsub) * K + csub;
    const size_t boff = (size_t)(n0 + rsub) * K + csub;

    f32x4 acc[4][4];
#pragma unroll
    for (int m = 0; m < 4; ++m)
#pragma unroll
        for (int n = 0; n < 4; ++n) acc[m][n] = (f32x4){0.f, 0.f, 0.f, 0.f};

    auto stage = [&](int buf, int k0) {
#pragma unroll
        for (int it = 0; it < 4; ++it) {
            const int g = it * 4 + wave;        // 8-row group 0..15
            GL16(A + aoff + (size_t)g * 8 * K + k0, &As[buf][g * 512]);
            GL16(Bw + boff + (size_t)g * 8 * K + k0, &Bs[buf][g * 512]);
        }
    };
    auto compute = [&](int buf) {
#pragma unroll
        for (int kh = 0; kh < 2; ++kh) {
            u16x8 af[4], bfr[4];
#pragma unroll
            for (int m = 0; m < 4; ++m) {
                int row = wr * 64 + m * 16 + lr;
                int cidx = (kh * 4 + lg) ^ (lr & 7);
                af[m] = *reinterpret_cast<const u16x8*>(&As[buf][row * 64 + cidx * 8]);
            }
#pragma unroll
            for (int n = 0; n < 4; ++n) {
                int row = wc * 64 + n * 16 + lr;
                int cidx = (kh * 4 + lg) ^ (lr & 7);
                bfr[n] = *reinterpret_cast<const u16x8*>(&Bs[buf][row * 64 + cidx * 8]);
            }
#pragma unroll
            for (int m = 0; m < 4; ++m)
#pragma unroll
                for (int n = 0; n < 4; ++n)
                    acc[m][n] = __builtin_amdgcn_mfma_f32_16x16x32_bf16(
                        __builtin_bit_cast(bf16x8, af[m]), __builtin_bit_cast(bf16x8, bfr[n]),
                        acc[m][n], 0, 0, 0);
        }
    };

    stage(0, 0);
    __syncthreads();
    int cur = 0;
    for (int k0 = 64; k0 < K; k0 += 64) {
        stage(cur ^ 1, k0);
        compute(cur);
        __syncthreads();
        cur ^= 1;
    }
    compute(cur);

#pragma unroll
    for (int n = 0; n < 4; ++n) {
        const int col = n0 + wc * 64 + n * 16 + lr;
        const float bv = bias ? bias[col] : 0.f;
        if (VPOSE && col >= 2048) {
            // V column: scatter transposed into VT[hh][b][d][s]
            const int hh = (col - 2048) >> 6, d = col & 63;
#pragma unroll
            for (int m = 0; m < 4; ++m) {
                const int rbase = m0 + wr * 64 + m * 16 + lg * 4;
                const int sb = rbase & 7, ss = rbase >> 3;
#pragma unroll
                for (int j = 0; j < 4; ++j) {
                    float v = acc[m][n][j] + bv;
                    VT[((size_t)((hh * 8 + sb + j) * 64 + d)) * 1024 + ss] = f2bf(v);
                }
            }
        } else {
#pragma unroll
            for (int m = 0; m < 4; ++m) {
#pragma unroll
                for (int j = 0; j < 4; ++j) {
                    const int row = m0 + wr * 64 + m * 16 + lg * 4 + j;
                    float v = acc[m][n][j] + bv;
                    if (GELU) v = 0.5f * v * (1.f + erff(v * 0.70710678118654752f));
                    store_out(C, (size_t)row * N + col, v);
                }
            }
        }
    }
}

// ---------- MFMA flash attention, GL16-staged K/V + double buffer ----------
// K from qkvB (row-major per token); V from VT[hh][b][d][s] (pre-transposed by
// the qkv GEMM). Both staged via global_load_lds with pre-swizzled source so
// LDS[row][chunk c] holds source chunk c^(row&7); reads use the same XOR.
__global__ __launch_bounds__(256) void k_fmfma(const unsigned short* __restrict__ qkvb,
                                               const unsigned short* __restrict__ VT,
                                               unsigned short* __restrict__ outb, int ostride) {
    __shared__ unsigned short Ks[2][4096];
    __shared__ unsigned short Vs[2][4096];
    __shared__ unsigned short Pl[4 * 16 * 72];
    const int tid = threadIdx.x;
    const int lane = tid & 63, wave = tid >> 6;
    const int lr = lane & 15, lg = lane >> 4;
    const int s0 = blockIdx.x * 64;
    const int bh = blockIdx.y;
    const int b = bh >> 4, hh = bh & 15;
    const int hb = hh * 64;

    // Q B-fragments direct from gmem
    u16x8 qf[2];
    {
        const size_t qb = (size_t)((s0 + wave * 16 + lr) * 8 + b) * 3072 + hb;
#pragma unroll
        for (int ks = 0; ks < 2; ++ks)
            qf[ks] = *reinterpret_cast<const u16x8*>(qkvb + qb + ks * 32 + lg * 8);
    }
    // staging bases (kt-independent part)
    const int rsub = lane >> 3;                 // row within 8-row group
    const int csub = ((lane & 7) ^ rsub) * 8;   // pre-swizzled chunk (shorts)
    // K row = key s' = kt*64 + g*8 + rsub, token = s'*8+b:
    const unsigned short* kS = qkvb + (size_t)((rsub) * 8 + b) * 3072 + 1024 + hb + csub;
    // V row = d = g*8 + rsub: VT[((hh*8+b)*64 + d)*1024 + kt*64 + csub]
    const unsigned short* vS = VT + ((size_t)((hh * 8 + b) * 64 + rsub)) * 1024 + csub;

    float m_old = -1e30f, l_run = 0.f;
    f32x4 oacc[4];
#pragma unroll
    for (int n = 0; n < 4; ++n) oacc[n] = (f32x4){0.f, 0.f, 0.f, 0.f};
    unsigned short* myP = Pl + wave * (16 * 72);

    auto stage = [&](int buf, int kt) {
#pragma unroll
        for (int it = 0; it < 2; ++it) {
            const int g = it * 4 + wave;  // 8-row group 0..7
            GL16(kS + ((size_t)(kt * 64 + g * 8) * 8) * 3072, &Ks[buf][g * 512]);
            GL16(vS + (size_t)g * 8 * 1024 + kt * 64, &Vs[buf][g * 512]);
        }
    };

    stage(0, 0);
    __syncthreads();
    int cur = 0;
    for (int kt = 0; kt < 16; ++kt) {
        if (kt < 15) stage(cur ^ 1, kt + 1);   // prefetch; drained by barrier below
        // ---- QK^T: C[key][qrow] = mfma(K, Q) ----
        f32x4 sacc[4];
#pragma unroll
        for (int n = 0; n < 4; ++n) sacc[n] = (f32x4){0.f, 0.f, 0.f, 0.f};
#pragma unroll
        for (int ks = 0; ks < 2; ++ks) {
#pragma unroll
            for (int n = 0; n < 4; ++n) {
                int row = n * 16 + lr;
                int cidx = (ks * 4 + lg) ^ (lr & 7);
                u16x8 kf = *reinterpret_cast<const u16x8*>(&Ks[cur][row * 64 + cidx * 8]);
                sacc[n] = __builtin_amdgcn_mfma_f32_16x16x32_bf16(
                    __builtin_bit_cast(bf16x8, kf), __builtin_bit_cast(bf16x8, qf[ks]),
                    sacc[n], 0, 0, 0);
            }
        }
        // ---- online softmax over 64 keys for qrow = lr ----
        float pmax = -1e30f;
#pragma unroll
        for (int n = 0; n < 4; ++n)
#pragma unroll
            for (int j = 0; j < 4; ++j) { sacc[n][j] *= 0.125f; pmax = fmaxf(pmax, sacc[n][j]); }
        pmax = fmaxf(pmax, __shfl_xor(pmax, 16, 64));
        pmax = fmaxf(pmax, __shfl_xor(pmax, 32, 64));
        const float m_new = fmaxf(m_old, pmax);
        const float corr = __expf(m_old - m_new);
        float pv[16];
        float psum = 0.f;
#pragma unroll
        for (int n = 0; n < 4; ++n)
#pragma unroll
            for (int j = 0; j < 4; ++j) { float e = __expf(sacc[n][j] - m_new); pv[n * 4 + j] = e; psum += e; }
        psum += __shfl_xor(psum, 16, 64);
        psum += __shfl_xor(psum, 32, 64);
        l_run = l_run * corr + psum;
        m_old = m_new;
#pragma unroll
        for (int n = 0; n < 4; ++n)
#pragma unroll
            for (int t2 = 0; t2 < 2; ++t2) {
                int key = n * 16 + lg * 4 + t2 * 2;
                unsigned int pk = (unsigned int)f2bf(pv[n * 4 + t2 * 2]) |
                                  ((unsigned int)f2bf(pv[n * 4 + t2 * 2 + 1]) << 16);
                *reinterpret_cast<unsigned int*>(&myP[lr * 72 + key]) = pk;
            }
#pragma unroll
        for (int j = 0; j < 4; ++j) {
            float cj = __shfl(corr, lg * 4 + j, 64);
#pragma unroll
            for (int n = 0; n < 4; ++n) oacc[n][j] *= cj;
        }
        // ---- PV: O[qrow][d] += P[qrow][key] * V[key][d]  (B-frag from Vs) ----
#pragma unroll
        for (int ks = 0; ks < 2; ++ks) {
            u16x8 pa = *reinterpret_cast<const u16x8*>(&myP[lr * 72 + ks * 32 + lg * 8]);
#pragma unroll
            for (int n = 0; n < 4; ++n) {
                int row = n * 16 + lr;   // d
                int cidx = (ks * 4 + lg) ^ (lr & 7);
                u16x8 vf = *reinterpret_cast<const u16x8*>(&Vs[cur][row * 64 + cidx * 8]);
                oacc[n] = __builtin_amdgcn_mfma_f32_16x16x32_bf16(
                    __builtin_bit_cast(bf16x8, pa), __builtin_bit_cast(bf16x8, vf),
                    oacc[n], 0, 0, 0);
            }
        }
        __syncthreads();   // drains prefetch (vmcnt 0) + protects Ks/Vs[cur] reuse
        cur ^= 1;
    }
    const float linv = 1.f / l_run;
#pragma unroll
    for (int j = 0; j < 4; ++j) {
        float lj = __shfl(linv, lg * 4 + j, 64);
        const size_t rowb = (size_t)((s0 + wave * 16 + lg * 4 + j) * 8 + b) * ostride + hb;
#pragma unroll
        for (int n = 0; n < 4; ++n)
            outb[rowb + n * 16 + lr] = f2bf(oacc[n][j] * lj);
    }
}

// ---------- layernorm over D=1024: out = LN(x + r)*g + be ----------
__global__ __launch_bounds__(256) void k_ln(const float* __restrict__ xf, const unsigned short* __restrict__ xb,
                                            const float* __restrict__ r,
                                            const float* __restrict__ g, const float* __restrict__ be,
                                            float* __restrict__ outf, unsigned short* __restrict__ outb) {
    const int row = blockIdx.x, tid = threadIdx.x;
    const size_t base = (size_t)row * 1024 + tid * 4;
    float x0, x1, x2, x3;
    if (xf) {
        float4 xv = *reinterpret_cast<const float4*>(xf + base);
        x0 = xv.x; x1 = xv.y; x2 = xv.z; x3 = xv.w;
    } else {
        u16x4 xv = *reinterpret_cast<const u16x4*>(xb + base);
        x0 = bf2f(xv[0]); x1 = bf2f(xv[1]); x2 = bf2f(xv[2]); x3 = bf2f(xv[3]);
    }
    float4 rv = *reinterpret_cast<const float4*>(r + base);
    float t0 = x0 + rv.x, t1 = x1 + rv.y, t2 = x2 + rv.z, t3 = x3 + rv.w;
    float s = t0 + t1 + t2 + t3;
    float ss = t0 * t0 + t1 * t1 + t2 * t2 + t3 * t3;
#pragma unroll
    for (int m = 1; m < 64; m <<= 1) { s += __shfl_xor(s, m, 64); ss += __shfl_xor(ss, m, 64); }
    __shared__ float red[8];
    const int wave = tid >> 6, lane = tid & 63;
    if (lane == 0) { red[wave] = s; red[4 + wave] = ss; }
    __syncthreads();
    s = red[0] + red[1] + red[2] + red[3];
    ss = red[4] + red[5] + red[6] + red[7];
    const float mean = s * (1.f / 1024.f);
    const float var = ss * (1.f / 1024.f) - mean * mean;
    const float rstd = rsqrtf(var + 1e-5f);
    float4 gv = *reinterpret_cast<const float4*>(g + tid * 4);
    float4 bv = *reinterpret_cast<const float4*>(be + tid * 4);
    float o0 = (t0 - mean) * rstd * gv.x + bv.x;
    float o1 = (t1 - mean) * rstd * gv.y + bv.y;
    float o2 = (t2 - mean) * rstd * gv.z + bv.z;
    float o3 = (t3 - mean) * rstd * gv.w + bv.w;
    if (outf) {
        float4 ov = {o0, o1, o2, o3};
        *reinterpret_cast<float4*>(outf + base) = ov;
    }
    if (outb) {
        u16x4 q; q[0] = f2bf(o0); q[1] = f2bf(o1); q[2] = f2bf(o2); q[3] = f2bf(o3);
        *reinterpret_cast<u16x4*>(outb + base) = q;
    }
}

// ---------- host ----------
extern "C" void kernel_launch(void* const* d_in, const int* in_sizes, int n_in,
                              void* d_out, int out_size, void* d_ws, size_t ws_size,
                              hipStream_t stream) {
    const float* src   = (const float*)d_in[0];
    const float* alpha = (const float*)d_in[1];
    const float* w_in  = (const float*)d_in[2];
    const float* b_in  = (const float*)d_in[3];
    const float* w_out = (const float*)d_in[4];
    const float* b_out = (const float*)d_in[5];
    const float* w1    = (const float*)d_in[6];
    const float* b1    = (const float*)d_in[7];
    const float* w2    = (const float*)d_in[8];
    const float* b2    = (const float*)d_in[9];
    const float* g1    = (const float*)d_in[10];
    const float* be1   = (const float*)d_in[11];
    const float* g2    = (const float*)d_in[12];
    const float* be2   = (const float*)d_in[13];

    char* ws = (char*)d_ws;
    size_t off = 0;
    auto alloc = [&](size_t bytes) { size_t r = off; off += (bytes + 255) & ~(size_t)255; return r; };
    float* P              = (float*)(ws + alloc(1024));
    float* pmax           = (float*)(ws + alloc(16 * 256 * 4));
    float* psum           = (float*)(ws + alloc(16 * 256 * 4));
    unsigned short* WinQ  = (unsigned short*)(ws + alloc((size_t)4 * 3072 * 1024 * 2));  // 25.2 MB
    unsigned short* WoutC = (unsigned short*)(ws + alloc((size_t)1024 * 4096 * 2));      // 8.4 MB
    unsigned short* W1m   = (unsigned short*)(ws + alloc((size_t)4096 * 1024 * 2));
    unsigned short* W2m   = (unsigned short*)(ws + alloc((size_t)1024 * 4096 * 2));
    float* b1m            = (float*)(ws + alloc(4096 * 4));
    float* b2m            = (float*)(ws + alloc(1024 * 4));
    float* bOm            = (float*)(ws + alloc(1024 * 4));
    unsigned short* Xbf   = (unsigned short*)(ws + alloc((size_t)MM * 1024 * 2));        // 16.8 MB
    unsigned short* attnC = (unsigned short*)(ws + alloc((size_t)MM * 4096 * 2));        // 67.1 MB
    unsigned short* VTb   = (unsigned short*)(ws + alloc((size_t)MM * 1024 * 2));        // 16.8 MB (per-branch V^T)
    unsigned short* qkvB  = (unsigned short*)(ws + alloc((size_t)MM * 3072 * 2));        // 50.3 MB
    unsigned short* h     = attnC;  // overlay: h == attnC size; attnC dead after out-proj
    if (ws_size < off) return;

    float* outF = (float*)d_out;    // src2 / y scratch, then final output

    k_stats<<<dim3(256, 16), 256, 0, stream>>>(w_in, w_out, w1, w2, pmax, psum);
    k_params<<<1, 256, 0, stream>>>(pmax, psum, alpha, P);
    {
        int n = 4 * 3072 * 1024;
        k_quant<<<(n + 255) / 256, 256, 0, stream>>>(w_in, WinQ, P, 3072 * 1024, 0, n);
        k_qcat<<<(4194304 + 255) / 256, 256, 0, stream>>>(w_out, WoutC, P);
        n = 4096 * 1024;
        k_mix<<<(n + 255) / 256, 256, 0, stream>>>(w1, W1m, P, 8, 1, n);
        k_mix<<<(n + 255) / 256, 256, 0, stream>>>(w2, W2m, P, 12, 2, n);
        k_mixb<<<(4096 + 255) / 256, 256, 0, stream>>>(b1, b1m, P, 1, 4096);
        k_mixb<<<(1024 + 255) / 256, 256, 0, stream>>>(b2, b2m, P, 2, 1024);
        k_mixb<<<(1024 + 255) / 256, 256, 0, stream>>>(b_out, bOm, P, 0, 1024);
        k_cast<<<(2097152 + 255) / 256, 256, 0, stream>>>(src, Xbf, 2097152);
    }
    // 4 branches: qkv GEMM (V transposed into VTb) then flash into attnC columns
    for (int i = 0; i < 4; ++i) {
        k_gemm_bt<unsigned short, false, true><<<dim3(24, 64), 256, 0, stream>>>(
            Xbf, WinQ + (size_t)i * 3072 * 1024, qkvB, b_in + i * 3072, VTb, MM, 3072, 1024, 1, 8);
        k_fmfma<<<dim3(16, 128), 256, 0, stream>>>(qkvB, VTb, attnC + i * 1024, 4096);
    }
    // fused out-proj: src2 = attnC @ WoutC^T + bOm   (K = 4096, writes d_out as scratch)
    k_gemm_bt<float, false, false><<<dim3(8, 64), 256, 0, stream>>>(
        attnC, WoutC, outF, bOm, nullptr, MM, 1024, 4096, 4, 2);
    // x = LN(src + src2) -> bf16 only
    k_ln<<<MM, 256, 0, stream>>>(src, nullptr, outF, g1, be1, nullptr, Xbf);
    // h = gelu(x @ W1m^T + b1m)
    k_gemm_bt<unsigned short, true, false><<<dim3(32, 64), 256, 0, stream>>>(
        Xbf, W1m, h, b1m, nullptr, MM, 4096, 1024, 1, 8);
    // y = h @ W2m^T + b2m  (overwrites d_out)
    k_gemm_bt<float, false, false><<<dim3(8, 64), 256, 0, stream>>>(
        h, W2m, outF, b2m, nullptr, MM, 1024, 4096, 4, 2);
    // out = LN(x + y)
    k_ln<<<MM, 256, 0, stream>>>(nullptr, Xbf, outF, g2, be2, outF, nullptr);
}

// Round 9
// 995.095 us; speedup vs baseline: 1.2656x; 1.2656x over previous
//
#include <hip/hip_runtime.h>
#include <hip/hip_bf16.h>

// ---------- types ----------
typedef __attribute__((ext_vector_type(8))) unsigned short u16x8;
typedef __attribute__((ext_vector_type(4))) unsigned short u16x4;
typedef __attribute__((ext_vector_type(4))) int            i32x4;
typedef __attribute__((ext_vector_type(8))) __bf16         bf16x8;
typedef __attribute__((ext_vector_type(4))) float          f32x4;

#define SS 1024
#define BB 8
#define DD 1024
#define HH 16
#define HDD 64
#define FF 4096
#define MM 8192   // S*B rows

// async global->LDS, 16B per lane; LDS dest is wave-uniform base + lane*16
#define GL16(g, l) __builtin_amdgcn_global_load_lds( \
    (__attribute__((address_space(1))) const void*)(g), \
    (__attribute__((address_space(3))) void*)(l), 16, 0, 0)

__device__ __forceinline__ float bf2f(unsigned short u) {
    return __uint_as_float(((unsigned int)u) << 16);
}
__device__ __forceinline__ unsigned short f2bf(float f) {
    unsigned int u = __float_as_uint(f);
    unsigned int r = (u + 0x7fffu + ((u >> 16) & 1u)) >> 16;  // RNE
    return (unsigned short)r;
}
__device__ __forceinline__ float quantv(float w, float som, float qm) {
    if (qm == 0.f) {  // 1-bit: sign(w)*mean|w|
        float sgn = (w > 0.f) ? 1.f : ((w < 0.f) ? -1.f : 0.f);
        return sgn * som;
    }
    if (som == 0.f) return 0.f;
    float q = rintf(w / som);
    q = fminf(fmaxf(q, -qm - 1.f), qm);
    return q * som;
}

// ---------- stats: per-tensor max|.|, sum|.| over 16 weight tensors + src ----------
__global__ __launch_bounds__(256) void k_stats(const float* __restrict__ w_in, const float* __restrict__ w_out,
                                               const float* __restrict__ w1, const float* __restrict__ w2,
                                               const float* __restrict__ src,
                                               float* __restrict__ pmax, float* __restrict__ psum) {
    const int t = blockIdx.y, blk = blockIdx.x, tid = threadIdx.x;
    const float* base; int n;
    if (t < 4)       { base = w_in  + (size_t)t * 3145728;     n = 3145728; }
    else if (t < 8)  { base = w_out + (size_t)(t-4) * 1048576; n = 1048576; }
    else if (t < 12) { base = w1    + (size_t)(t-8) * 4194304; n = 4194304; }
    else if (t < 16) { base = w2    + (size_t)(t-12) * 4194304; n = 4194304; }
    else             { base = src;                             n = 8388608; }
    const int n4 = n >> 2;
    float vmax = 0.f, vsum = 0.f;
    for (int i = blk * 256 + tid; i < n4; i += 65536) {
        float4 v = reinterpret_cast<const float4*>(base)[i];
        float a0 = fabsf(v.x), a1 = fabsf(v.y), a2 = fabsf(v.z), a3 = fabsf(v.w);
        vmax = fmaxf(vmax, fmaxf(fmaxf(a0, a1), fmaxf(a2, a3)));
        vsum += (a0 + a1) + (a2 + a3);
    }
#pragma unroll
    for (int m = 1; m < 64; m <<= 1) { vmax = fmaxf(vmax, __shfl_xor(vmax, m, 64)); vsum += __shfl_xor(vsum, m, 64); }
    __shared__ float sm[4], su[4];
    const int wave = tid >> 6, lane = tid & 63;
    if (lane == 0) { sm[wave] = vmax; su[wave] = vsum; }
    __syncthreads();
    if (tid == 0) {
        pmax[t * 256 + blk] = fmaxf(fmaxf(sm[0], sm[1]), fmaxf(sm[2], sm[3]));
        psum[t * 256 + blk] = (su[0] + su[1]) + (su[2] + su[3]);
    }
}

// ---------- params: final reduce + softmax(alpha); P[50] = src absmax/127 ----------
__global__ __launch_bounds__(256) void k_params(const float* __restrict__ pmax, const float* __restrict__ psum,
                                                const float* __restrict__ alpha, float* __restrict__ P) {
    __shared__ float rm[256], rs[256];
    const int tid = threadIdx.x;
    for (int t = 0; t < 17; ++t) {
        rm[tid] = pmax[t * 256 + tid];
        rs[tid] = psum[t * 256 + tid];
        __syncthreads();
        for (int s = 128; s > 0; s >>= 1) {
            if (tid < s) { rm[tid] = fmaxf(rm[tid], rm[tid + s]); rs[tid] += rs[tid + s]; }
            __syncthreads();
        }
        if (tid == 0) {
            if (t == 16) {
                P[50] = rm[0] * (1.f / 127.f);
            } else {
                const int nbits[4] = {1, 2, 4, 8};
                const int nb = nbits[t & 3];
                float nsize = (t < 4) ? 3145728.f : ((t < 8) ? 1048576.f : 4194304.f);
                if (nb == 1) { P[16 + 2*t] = rs[0] / nsize; P[17 + 2*t] = 0.f; }
                else { float qm = (float)((1 << (nb - 1)) - 1); P[16 + 2*t] = rm[0] / qm; P[17 + 2*t] = qm; }
            }
        }
        __syncthreads();
    }
    if (tid < 3) {
        float a[4], mx = -1e30f;
#pragma unroll
        for (int i = 0; i < 4; ++i) { a[i] = alpha[tid * 4 + i]; mx = fmaxf(mx, a[i]); }
        float e[4], ssum = 0.f;
#pragma unroll
        for (int i = 0; i < 4; ++i) { e[i] = expf(a[i] - mx); ssum += e[i]; }
#pragma unroll
        for (int i = 0; i < 4; ++i) P[tid * 4 + i] = e[i] / ssum;
    }
}

// ---------- quantize in-proj weights -> i8 (integer part is EXACT per reference) ----------
__global__ __launch_bounds__(256) void k_quant8(const float* __restrict__ w, signed char* __restrict__ out,
                                                const float* __restrict__ P, int per_tensor, int tbase, int ntot) {
    int i = blockIdx.x * 256 + threadIdx.x;
    if (i >= ntot) return;
    int t = tbase + i / per_tensor;
    float som = P[16 + 2*t], qm = P[17 + 2*t];
    float v;
    float x = w[i];
    if (qm == 0.f)      v = (x > 0.f) ? 1.f : ((x < 0.f) ? -1.f : 0.f);
    else if (som == 0.f) v = 0.f;
    else                v = fminf(fmaxf(rintf(x / som), -qm - 1.f), qm);
    out[i] = (signed char)(int)v;
}

// ---------- quantize src -> i8 with per-tensor scale P[50] ----------
__global__ __launch_bounds__(256) void k_si8(const float* __restrict__ in, signed char* __restrict__ out,
                                             const float* __restrict__ P, int n4) {
    int i = blockIdx.x * 256 + threadIdx.x;
    if (i >= n4) return;
    const float sa = P[50];
    const float inv = (sa > 0.f) ? 1.f / sa : 0.f;
    float4 v = reinterpret_cast<const float4*>(in)[i];
    char4 o;
    o.x = (signed char)(int)fminf(fmaxf(rintf(v.x * inv), -127.f), 127.f);
    o.y = (signed char)(int)fminf(fmaxf(rintf(v.y * inv), -127.f), 127.f);
    o.z = (signed char)(int)fminf(fmaxf(rintf(v.z * inv), -127.f), 127.f);
    o.w = (signed char)(int)fminf(fmaxf(rintf(v.w * inv), -127.f), 127.f);
    reinterpret_cast<char4*>(out)[i] = o;
}

// ---------- out-proj: quantize + scale by probs[0][i], K-concat layout ----------
__global__ __launch_bounds__(256) void k_qcat(const float* __restrict__ w_out, unsigned short* __restrict__ out,
                                              const float* __restrict__ P) {
    int j = blockIdx.x * 256 + threadIdx.x;
    if (j >= 4194304) return;
    int d = j >> 12, rr = j & 4095, i = rr >> 10, e = rr & 1023;
    int t = 4 + i;
    float v = quantv(w_out[((size_t)i << 20) + d * 1024 + e], P[16 + 2*t], P[17 + 2*t]);
    out[j] = f2bf(P[i] * v);
}

// ---------- mix quantized FFN weights across branches -> bf16 ----------
__global__ __launch_bounds__(256) void k_mix(const float* __restrict__ w, unsigned short* __restrict__ out,
                                             const float* __restrict__ P, int tbase, int prow, int sz) {
    int i = blockIdx.x * 256 + threadIdx.x;
    if (i >= sz) return;
    float acc = 0.f;
#pragma unroll
    for (int br = 0; br < 4; ++br) {
        int t = tbase + br;
        acc += P[prow * 4 + br] * quantv(w[(size_t)br * sz + i], P[16 + 2*t], P[17 + 2*t]);
    }
    out[i] = f2bf(acc);
}
__global__ __launch_bounds__(256) void k_mixb(const float* __restrict__ b, float* __restrict__ out,
                                              const float* __restrict__ P, int prow, int n) {
    int i = blockIdx.x * 256 + threadIdx.x;
    if (i >= n) return;
    float acc = 0.f;
#pragma unroll
    for (int br = 0; br < 4; ++br) acc += P[prow * 4 + br] * b[(size_t)br * n + i];
    out[i] = acc;
}

// ---------- bf16 GEMM (R5 structure, best-measured): C = act(A @ Bw^T + bias) ----------
__device__ __forceinline__ void store_out(float* C, size_t idx, float v) { C[idx] = v; }
__device__ __forceinline__ void store_out(unsigned short* C, size_t idx, float v) { C[idx] = f2bf(v); }

template <typename OutT, bool GELU>
__global__ __launch_bounds__(256) void k_gemm_bt(const unsigned short* __restrict__ A,
                                                 const unsigned short* __restrict__ Bw,
                                                 OutT* __restrict__ C,
                                                 const float* __restrict__ bias,
                                                 int M, int N, int K, int XM, int XN) {
    const int gx = gridDim.x, gy = gridDim.y;
    const int flat = blockIdx.x + gx * blockIdx.y;
    const int xcd = flat & 7, r = flat >> 3;
    const int nloc = gx / XN, mloc = gy / XM;
    const int cm = xcd / XN, cn = xcd - cm * XN;
    const int by = cm * mloc + r / nloc;
    const int bx = cn * nloc + (r - (r / nloc) * nloc);

    __shared__ unsigned short As[2][128 * 64];
    __shared__ unsigned short Bs[2][128 * 64];
    const int tid = threadIdx.x;
    const int m0 = by * 128, n0 = bx * 128;
    const int lane = tid & 63, wave = tid >> 6;
    const int wr = wave >> 1, wc = wave & 1;
    const int lr = lane & 15, lg = lane >> 4;
    const int rsub = lane >> 3;
    const int csub = ((lane & 7) ^ rsub) * 8;
    const size_t aoff = (size_t)(m0 + rsub) * K + csub;
    const size_t boff = (size_t)(n0 + rsub) * K + csub;

    f32x4 acc[4][4];
#pragma unroll
    for (int m = 0; m < 4; ++m)
#pragma unroll
        for (int n = 0; n < 4; ++n) acc[m][n] = (f32x4){0.f, 0.f, 0.f, 0.f};

    auto stage = [&](int buf, int k0) {
#pragma unroll
        for (int it = 0; it < 4; ++it) {
            const int g = it * 4 + wave;
            GL16(A + aoff + (size_t)g * 8 * K + k0, &As[buf][g * 512]);
            GL16(Bw + boff + (size_t)g * 8 * K + k0, &Bs[buf][g * 512]);
        }
    };
    auto compute = [&](int buf) {
#pragma unroll
        for (int kh = 0; kh < 2; ++kh) {
            u16x8 af[4], bfr[4];
#pragma unroll
            for (int m = 0; m < 4; ++m) {
                int row = wr * 64 + m * 16 + lr;
                int cidx = (kh * 4 + lg) ^ (lr & 7);
                af[m] = *reinterpret_cast<const u16x8*>(&As[buf][row * 64 + cidx * 8]);
            }
#pragma unroll
            for (int n = 0; n < 4; ++n) {
                int row = wc * 64 + n * 16 + lr;
                int cidx = (kh * 4 + lg) ^ (lr & 7);
                bfr[n] = *reinterpret_cast<const u16x8*>(&Bs[buf][row * 64 + cidx * 8]);
            }
#pragma unroll
            for (int m = 0; m < 4; ++m)
#pragma unroll
                for (int n = 0; n < 4; ++n)
                    acc[m][n] = __builtin_amdgcn_mfma_f32_16x16x32_bf16(
                        __builtin_bit_cast(bf16x8, af[m]), __builtin_bit_cast(bf16x8, bfr[n]),
                        acc[m][n], 0, 0, 0);
        }
    };

    stage(0, 0);
    __syncthreads();
    int cur = 0;
    for (int k0 = 64; k0 < K; k0 += 64) {
        stage(cur ^ 1, k0);
        compute(cur);
        __syncthreads();
        cur ^= 1;
    }
    compute(cur);

#pragma unroll
    for (int n = 0; n < 4; ++n) {
        const int col = n0 + wc * 64 + n * 16 + lr;
        const float bv = bias ? bias[col] : 0.f;
#pragma unroll
        for (int m = 0; m < 4; ++m) {
#pragma unroll
            for (int j = 0; j < 4; ++j) {
                const int row = m0 + wr * 64 + m * 16 + lg * 4 + j;
                float v = acc[m][n][j] + bv;
                if (GELU) v = 0.5f * v * (1.f + erff(v * 0.70710678118654752f));
                store_out(C, (size_t)row * N + col, v);
            }
        }
    }
}

// ---------- i8 GEMM for qkv: C_bf16 = (A_i8 @ B_i8^T) * sa*st + bias ----------
// Same byte geometry as bf16 kernel (rows = 128B, 16B chunks, same XOR swizzle,
// GL16 staging), BK=128 i8 -> half the iterations, mfma_i32_16x16x64_i8.
__global__ __launch_bounds__(256) void k_gemm_i8(const signed char* __restrict__ A,
                                                 const signed char* __restrict__ Bw,
                                                 unsigned short* __restrict__ C,
                                                 const float* __restrict__ bias,
                                                 const float* __restrict__ P, int tIdx,
                                                 int M, int N, int K, int XM, int XN) {
    const int gx = gridDim.x, gy = gridDim.y;
    const int flat = blockIdx.x + gx * blockIdx.y;
    const int xcd = flat & 7, r = flat >> 3;
    const int nloc = gx / XN, mloc = gy / XM;
    const int cm = xcd / XN, cn = xcd - cm * XN;
    const int by = cm * mloc + r / nloc;
    const int bx = cn * nloc + (r - (r / nloc) * nloc);

    __shared__ signed char As[2][128 * 128];
    __shared__ signed char Bs[2][128 * 128];
    const int tid = threadIdx.x;
    const int m0 = by * 128, n0 = bx * 128;
    const int lane = tid & 63, wave = tid >> 6;
    const int wr = wave >> 1, wc = wave & 1;
    const int lr = lane & 15, lg = lane >> 4;
    const int rsub = lane >> 3;                   // row within 8-row group
    const int csub = ((lane & 7) ^ rsub) * 16;    // pre-swizzled chunk (bytes)
    const size_t aoff = (size_t)(m0 + rsub) * K + csub;
    const size_t boff = (size_t)(n0 + rsub) * K + csub;

    i32x4 acc[4][4];
#pragma unroll
    for (int m = 0; m < 4; ++m)
#pragma unroll
        for (int n = 0; n < 4; ++n) acc[m][n] = (i32x4){0, 0, 0, 0};

    auto stage = [&](int buf, int k0) {
#pragma unroll
        for (int it = 0; it < 4; ++it) {
            const int g = it * 4 + wave;          // 8-row group 0..15
            GL16(A + aoff + (size_t)g * 8 * K + k0, &As[buf][g * 1024]);
            GL16(Bw + boff + (size_t)g * 8 * K + k0, &Bs[buf][g * 1024]);
        }
    };
    auto compute = [&](int buf) {
#pragma unroll
        for (int kh = 0; kh < 2; ++kh) {          // two K=64 sub-steps
            i32x4 af[4], bfr[4];
#pragma unroll
            for (int m = 0; m < 4; ++m) {
                int row = wr * 64 + m * 16 + lr;
                int cidx = (kh * 4 + lg) ^ (lr & 7);
                af[m] = *reinterpret_cast<const i32x4*>(&As[buf][row * 128 + cidx * 16]);
            }
#pragma unroll
            for (int n = 0; n < 4; ++n) {
                int row = wc * 64 + n * 16 + lr;
                int cidx = (kh * 4 + lg) ^ (lr & 7);
                bfr[n] = *reinterpret_cast<const i32x4*>(&Bs[buf][row * 128 + cidx * 16]);
            }
#pragma unroll
            for (int m = 0; m < 4; ++m)
#pragma unroll
                for (int n = 0; n < 4; ++n)
                    acc[m][n] = __builtin_amdgcn_mfma_i32_16x16x64_i8(
                        af[m], bfr[n], acc[m][n], 0, 0, 0);
        }
    };

    stage(0, 0);
    __syncthreads();
    int cur = 0;
    for (int k0 = 128; k0 < K; k0 += 128) {
        stage(cur ^ 1, k0);
        compute(cur);
        __syncthreads();
        cur ^= 1;
    }
    compute(cur);

    const float sab = P[50] * P[16 + 2 * tIdx];
#pragma unroll
    for (int n = 0; n < 4; ++n) {
        const int col = n0 + wc * 64 + n * 16 + lr;
        const float bv = bias[col];
#pragma unroll
        for (int m = 0; m < 4; ++m) {
#pragma unroll
            for (int j = 0; j < 4; ++j) {
                const int row = m0 + wr * 64 + m * 16 + lg * 4 + j;
                float v = (float)acc[m][n][j] * sab + bv;
                C[(size_t)row * N + col] = f2bf(v);
            }
        }
    }
}

// ---------- MFMA flash attention (R5 version: strided qkv slice in, strided out) ----------
__global__ __launch_bounds__(256) void k_fmfma(const unsigned short* __restrict__ qkvb, int qstride,
                                               unsigned short* __restrict__ outb, int ostride) {
    __shared__ unsigned short Ks[64 * 64];
    __shared__ unsigned short Vt[64 * 64];
    __shared__ unsigned short Pl[4 * 16 * 72];
    const int tid = threadIdx.x;
    const int lane = tid & 63, wave = tid >> 6;
    const int lr = lane & 15, lg = lane >> 4;
    const int s0 = blockIdx.x * 64;
    const int bh = blockIdx.y;
    const int b = bh >> 4, hh = bh & 15;
    const int hb = hh * 64;

    u16x8 qf[2];
    {
        const size_t qb = (size_t)((s0 + wave * 16 + lr) * 8 + b) * qstride + hb;
#pragma unroll
        for (int ks = 0; ks < 2; ++ks)
            qf[ks] = *reinterpret_cast<const u16x8*>(qkvb + qb + ks * 32 + lg * 8);
    }
    float m_old = -1e30f, l_run = 0.f;
    f32x4 oacc[4];
#pragma unroll
    for (int n = 0; n < 4; ++n) oacc[n] = (f32x4){0.f, 0.f, 0.f, 0.f};
    unsigned short* myP = Pl + wave * (16 * 72);

    for (int kt = 0; kt < 16; ++kt) {
        __syncthreads();
#pragma unroll
        for (int it = 0; it < 2; ++it) {
            int c = tid + it * 256;
            int row = c >> 3, ch = c & 7;
            const size_t gb = (size_t)((kt * 64 + row) * 8 + b) * qstride + hb + ch * 8;
            int chs = ch ^ (row & 7);
            *reinterpret_cast<u16x8*>(&Ks[row * 64 + chs * 8]) =
                *reinterpret_cast<const u16x8*>(qkvb + gb + 1024);
            u16x8 vv = *reinterpret_cast<const u16x8*>(qkvb + gb + 2048);
            const int vbase = ((row >> 3) ^ ch) * 8 + (row & 7);
#pragma unroll
            for (int e = 0; e < 8; ++e) Vt[(ch * 8 + e) * 64 + vbase] = vv[e];
        }
        __syncthreads();
        f32x4 sacc[4];
#pragma unroll
        for (int n = 0; n < 4; ++n) sacc[n] = (f32x4){0.f, 0.f, 0.f, 0.f};
#pragma unroll
        for (int ks = 0; ks < 2; ++ks) {
#pragma unroll
            for (int n = 0; n < 4; ++n) {
                int row = n * 16 + lr;
                int cidx = (ks * 4 + lg) ^ (lr & 7);
                u16x8 kf = *reinterpret_cast<const u16x8*>(&Ks[row * 64 + cidx * 8]);
                sacc[n] = __builtin_amdgcn_mfma_f32_16x16x32_bf16(
                    __builtin_bit_cast(bf16x8, kf), __builtin_bit_cast(bf16x8, qf[ks]),
                    sacc[n], 0, 0, 0);
            }
        }
        float pmax = -1e30f;
#pragma unroll
        for (int n = 0; n < 4; ++n)
#pragma unroll
            for (int j = 0; j < 4; ++j) { sacc[n][j] *= 0.125f; pmax = fmaxf(pmax, sacc[n][j]); }
        pmax = fmaxf(pmax, __shfl_xor(pmax, 16, 64));
        pmax = fmaxf(pmax, __shfl_xor(pmax, 32, 64));
        const float m_new = fmaxf(m_old, pmax);
        const float corr = __expf(m_old - m_new);
        float pv[16];
        float psum = 0.f;
#pragma unroll
        for (int n = 0; n < 4; ++n)
#pragma unroll
            for (int j = 0; j < 4; ++j) { float e = __expf(sacc[n][j] - m_new); pv[n * 4 + j] = e; psum += e; }
        psum += __shfl_xor(psum, 16, 64);
        psum += __shfl_xor(psum, 32, 64);
        l_run = l_run * corr + psum;
        m_old = m_new;
#pragma unroll
        for (int n = 0; n < 4; ++n)
#pragma unroll
            for (int t2 = 0; t2 < 2; ++t2) {
                int key = n * 16 + lg * 4 + t2 * 2;
                unsigned int pk = (unsigned int)f2bf(pv[n * 4 + t2 * 2]) |
                                  ((unsigned int)f2bf(pv[n * 4 + t2 * 2 + 1]) << 16);
                *reinterpret_cast<unsigned int*>(&myP[lr * 72 + key]) = pk;
            }
#pragma unroll
        for (int j = 0; j < 4; ++j) {
            float cj = __shfl(corr, lg * 4 + j, 64);
#pragma unroll
            for (int n = 0; n < 4; ++n) oacc[n][j] *= cj;
        }
#pragma unroll
        for (int ks = 0; ks < 2; ++ks) {
            u16x8 pa = *reinterpret_cast<const u16x8*>(&myP[lr * 72 + ks * 32 + lg * 8]);
#pragma unroll
            for (int n = 0; n < 4; ++n) {
                int d = n * 16 + lr;
                int kcs = (ks * 4 + lg) ^ (d >> 3);
                u16x8 vf = *reinterpret_cast<const u16x8*>(&Vt[d * 64 + kcs * 8]);
                oacc[n] = __builtin_amdgcn_mfma_f32_16x16x32_bf16(
                    __builtin_bit_cast(bf16x8, pa), __builtin_bit_cast(bf16x8, vf),
                    oacc[n], 0, 0, 0);
            }
        }
    }
    const float linv = 1.f / l_run;
#pragma unroll
    for (int j = 0; j < 4; ++j) {
        float lj = __shfl(linv, lg * 4 + j, 64);
        const size_t rowb = (size_t)((s0 + wave * 16 + lg * 4 + j) * 8 + b) * ostride + hb;
#pragma unroll
        for (int n = 0; n < 4; ++n)
            outb[rowb + n * 16 + lr] = f2bf(oacc[n][j] * lj);
    }
}

// ---------- layernorm over D=1024: out = LN(x + r)*g + be ----------
__global__ __launch_bounds__(256) void k_ln(const float* __restrict__ xf, const unsigned short* __restrict__ xb,
                                            const float* __restrict__ r,
                                            const float* __restrict__ g, const float* __restrict__ be,
                                            float* __restrict__ outf, unsigned short* __restrict__ outb) {
    const int row = blockIdx.x, tid = threadIdx.x;
    const size_t base = (size_t)row * 1024 + tid * 4;
    float x0, x1, x2, x3;
    if (xf) {
        float4 xv = *reinterpret_cast<const float4*>(xf + base);
        x0 = xv.x; x1 = xv.y; x2 = xv.z; x3 = xv.w;
    } else {
        u16x4 xv = *reinterpret_cast<const u16x4*>(xb + base);
        x0 = bf2f(xv[0]); x1 = bf2f(xv[1]); x2 = bf2f(xv[2]); x3 = bf2f(xv[3]);
    }
    float4 rv = *reinterpret_cast<const float4*>(r + base);
    float t0 = x0 + rv.x, t1 = x1 + rv.y, t2 = x2 + rv.z, t3 = x3 + rv.w;
    float s = t0 + t1 + t2 + t3;
    float ss = t0 * t0 + t1 * t1 + t2 * t2 + t3 * t3;
#pragma unroll
    for (int m = 1; m < 64; m <<= 1) { s += __shfl_xor(s, m, 64); ss += __shfl_xor(ss, m, 64); }
    __shared__ float red[8];
    const int wave = tid >> 6, lane = tid & 63;
    if (lane == 0) { red[wave] = s; red[4 + wave] = ss; }
    __syncthreads();
    s = red[0] + red[1] + red[2] + red[3];
    ss = red[4] + red[5] + red[6] + red[7];
    const float mean = s * (1.f / 1024.f);
    const float var = ss * (1.f / 1024.f) - mean * mean;
    const float rstd = rsqrtf(var + 1e-5f);
    float4 gv = *reinterpret_cast<const float4*>(g + tid * 4);
    float4 bv = *reinterpret_cast<const float4*>(be + tid * 4);
    float o0 = (t0 - mean) * rstd * gv.x + bv.x;
    float o1 = (t1 - mean) * rstd * gv.y + bv.y;
    float o2 = (t2 - mean) * rstd * gv.z + bv.z;
    float o3 = (t3 - mean) * rstd * gv.w + bv.w;
    if (outf) {
        float4 ov = {o0, o1, o2, o3};
        *reinterpret_cast<float4*>(outf + base) = ov;
    }
    if (outb) {
        u16x4 q; q[0] = f2bf(o0); q[1] = f2bf(o1); q[2] = f2bf(o2); q[3] = f2bf(o3);
        *reinterpret_cast<u16x4*>(outb + base) = q;
    }
}

// ---------- host ----------
extern "C" void kernel_launch(void* const* d_in, const int* in_sizes, int n_in,
                              void* d_out, int out_size, void* d_ws, size_t ws_size,
                              hipStream_t stream) {
    const float* src   = (const float*)d_in[0];
    const float* alpha = (const float*)d_in[1];
    const float* w_in  = (const float*)d_in[2];
    const float* b_in  = (const float*)d_in[3];
    const float* w_out = (const float*)d_in[4];
    const float* b_out = (const float*)d_in[5];
    const float* w1    = (const float*)d_in[6];
    const float* b1    = (const float*)d_in[7];
    const float* w2    = (const float*)d_in[8];
    const float* b2    = (const float*)d_in[9];
    const float* g1    = (const float*)d_in[10];
    const float* be1   = (const float*)d_in[11];
    const float* g2    = (const float*)d_in[12];
    const float* be2   = (const float*)d_in[13];

    char* ws = (char*)d_ws;
    size_t off = 0;
    auto alloc = [&](size_t bytes) { size_t r = off; off += (bytes + 255) & ~(size_t)255; return r; };
    float* P              = (float*)(ws + alloc(1024));
    float* pmax           = (float*)(ws + alloc(17 * 256 * 4));
    float* psum           = (float*)(ws + alloc(17 * 256 * 4));
    signed char* WinQ8    = (signed char*)(ws + alloc((size_t)4 * 3072 * 1024));      // 12.6 MB i8
    unsigned short* WoutC = (unsigned short*)(ws + alloc((size_t)1024 * 4096 * 2));   // 8.4 MB
    unsigned short* W1m   = (unsigned short*)(ws + alloc((size_t)4096 * 1024 * 2));
    unsigned short* W2m   = (unsigned short*)(ws + alloc((size_t)1024 * 4096 * 2));
    float* b1m            = (float*)(ws + alloc(4096 * 4));
    float* b2m            = (float*)(ws + alloc(1024 * 4));
    float* bOm            = (float*)(ws + alloc(1024 * 4));
    signed char* Si8      = (signed char*)(ws + alloc((size_t)MM * 1024));            // 8.4 MB i8 src
    unsigned short* Xbf   = (unsigned short*)(ws + alloc((size_t)MM * 1024 * 2));     // 16.8 MB (LN1 out)
    unsigned short* attnC = (unsigned short*)(ws + alloc((size_t)MM * 4096 * 2));     // 67.1 MB
    unsigned short* qkvB  = (unsigned short*)(ws + alloc((size_t)MM * 3072 * 2));     // 50.3 MB
    unsigned short* h     = attnC;  // overlay: h == attnC size; attnC dead after out-proj
    if (ws_size < off) return;

    float* outF = (float*)d_out;    // src2 / y scratch, then final output

    k_stats<<<dim3(256, 17), 256, 0, stream>>>(w_in, w_out, w1, w2, src, pmax, psum);
    k_params<<<1, 256, 0, stream>>>(pmax, psum, alpha, P);
    {
        int n = 4 * 3072 * 1024;
        k_quant8<<<(n + 255) / 256, 256, 0, stream>>>(w_in, WinQ8, P, 3072 * 1024, 0, n);
        k_qcat<<<(4194304 + 255) / 256, 256, 0, stream>>>(w_out, WoutC, P);
        n = 4096 * 1024;
        k_mix<<<(n + 255) / 256, 256, 0, stream>>>(w1, W1m, P, 8, 1, n);
        k_mix<<<(n + 255) / 256, 256, 0, stream>>>(w2, W2m, P, 12, 2, n);
        k_mixb<<<(4096 + 255) / 256, 256, 0, stream>>>(b1, b1m, P, 1, 4096);
        k_mixb<<<(1024 + 255) / 256, 256, 0, stream>>>(b2, b2m, P, 2, 1024);
        k_mixb<<<(1024 + 255) / 256, 256, 0, stream>>>(b_out, bOm, P, 0, 1024);
        k_si8<<<(2097152 + 255) / 256, 256, 0, stream>>>(src, Si8, P, 2097152);
    }
    // 4 branches: i8 qkv GEMM (N=3072, K=1024, BK=128) then flash into attnC columns
    for (int i = 0; i < 4; ++i) {
        k_gemm_i8<<<dim3(24, 64), 256, 0, stream>>>(
            Si8, WinQ8 + (size_t)i * 3072 * 1024, qkvB, b_in + i * 3072, P, i, MM, 3072, 1024, 1, 8);
        k_fmfma<<<dim3(16, 128), 256, 0, stream>>>(qkvB, 3072, attnC + i * 1024, 4096);
    }
    // fused out-proj: src2 = attnC @ WoutC^T + bOm   (K = 4096, writes d_out as scratch)
    k_gemm_bt<float, false><<<dim3(8, 64), 256, 0, stream>>>(
        attnC, WoutC, outF, bOm, MM, 1024, 4096, 4, 2);
    // x = LN(src + src2) -> bf16 only
    k_ln<<<MM, 256, 0, stream>>>(src, nullptr, outF, g1, be1, nullptr, Xbf);
    // h = gelu(x @ W1m^T + b1m)
    k_gemm_bt<unsigned short, true><<<dim3(32, 64), 256, 0, stream>>>(
        Xbf, W1m, h, b1m, MM, 4096, 1024, 1, 8);
    // y = h @ W2m^T + b2m  (overwrites d_out)
    k_gemm_bt<float, false><<<dim3(8, 64), 256, 0, stream>>>(
        h, W2m, outF, b2m, MM, 1024, 4096, 4, 2);
    // out = LN(x + y)
    k_ln<<<MM, 256, 0, stream>>>(nullptr, Xbf, outF, g2, be2, outF, nullptr);
}